// Round 10
// baseline (495.655 us; speedup 1.0000x reference)
//
#include <hip/hip_runtime.h>

#define N_NODES 50000
#define N_EDGES 800000
#define IN_DIM  256
#define H1      512
#define H2      128

typedef __attribute__((ext_vector_type(8))) short  short8v;
typedef __attribute__((ext_vector_type(4))) float  float4v;
typedef __attribute__((ext_vector_type(4))) unsigned uint4v;

// split fp32 -> bf16 hi + bf16 lo (RNE both); v ~= hi + lo with ~16 mantissa bits
__device__ __forceinline__ void split_bf16(float v, unsigned short& h, unsigned short& l) {
    unsigned u = __builtin_bit_cast(unsigned, v);
    unsigned hr = (u + 0x7FFFu + ((u >> 16) & 1u)) >> 16;       // RNE to bf16
    float hf = __builtin_bit_cast(float, hr << 16);
    float lf = v - hf;
    unsigned ul = __builtin_bit_cast(unsigned, lf);
    unsigned lr = (ul + 0x7FFFu + ((ul >> 16) & 1u)) >> 16;
    h = (unsigned short)hr; l = (unsigned short)lr;
}

// ---------------- CSR build kernels ----------------
// Atomic write-through is 32B/sector (round-9 PMC: WRITE_SIZE = n_atomics*32B).
// So: histogram uses ONE int atomic per edge; deg/dinv/coef are derived from the
// CSR afterwards with coalesced passes (no float atomics at all).

__global__ void edge_hist_kernel(const int* __restrict__ col, int* cnt, int ne) {
    int e = blockIdx.x * blockDim.x + threadIdx.x;
    if (e < ne) atomicAdd(&cnt[col[e]], 1);
}

// hierarchical exclusive scan: per-block scan -> top scan -> add offsets
__global__ void scan_block_kernel(const int* __restrict__ cnt, int* __restrict__ part,
                                  int* __restrict__ bsum, int n) {
    __shared__ int s[256];
    int tid = threadIdx.x;
    int i = blockIdx.x * 256 + tid;
    int v = (i < n) ? cnt[i] : 0;
    s[tid] = v; __syncthreads();
#pragma unroll
    for (int d = 1; d < 256; d <<= 1) {
        int t = (tid >= d) ? s[tid - d] : 0; __syncthreads();
        s[tid] += t; __syncthreads();
    }
    if (i < n) part[i] = s[tid] - v;           // exclusive within block
    if (tid == 255) bsum[blockIdx.x] = s[255]; // block total
}

__global__ void scan_tops_kernel(const int* __restrict__ bsum, int* __restrict__ boff, int nb) {
    __shared__ int s[256];
    int tid = threadIdx.x;
    int v = (tid < nb) ? bsum[tid] : 0;
    s[tid] = v; __syncthreads();
#pragma unroll
    for (int d = 1; d < 256; d <<= 1) {
        int t = (tid >= d) ? s[tid - d] : 0; __syncthreads();
        s[tid] += t; __syncthreads();
    }
    if (tid < nb) boff[tid] = s[tid] - v;      // exclusive across blocks
}

__global__ void scan_add_kernel(const int* __restrict__ part, const int* __restrict__ boff,
                                int* __restrict__ ptr, int* __restrict__ fill, int n) {
    int i = blockIdx.x * 256 + threadIdx.x;
    if (i < n) {
        int p = part[i] + boff[blockIdx.x];
        ptr[i] = p; fill[i] = p;
    }
    if (i == 0) ptr[n] = N_EDGES;              // total edges known at compile time
}

// place edges: record (src, raw ew bits); coef filled later (no dinv dependency)
__global__ void scatter_kernel(const int* __restrict__ row, const int* __restrict__ col,
                               const float* __restrict__ ew,
                               int* fill, int2* __restrict__ edges, int ne) {
    int e = blockIdx.x * blockDim.x + threadIdx.x;
    if (e < ne) {
        int r = row[e], c = col[e];
        int pos = atomicAdd(&fill[c], 1);
        edges[pos] = make_int2(r, __float_as_int(ew[e]));
    }
}

// deg from CSR (coalesced-ish slot sum) -> dinv = rsqrt(1 + sum ew)
__global__ void degdinv_kernel(const int* __restrict__ ptr, const int2* __restrict__ edges,
                               float* __restrict__ dinv, int n) {
    int i = blockIdx.x * blockDim.x + threadIdx.x;
    if (i < n) {
        float s = 1.0f;                        // self-loop weight
        int e1 = ptr[i + 1];
        for (int j = ptr[i]; j < e1; ++j) s += __int_as_float(edges[j].y);
        dinv[i] = rsqrtf(s);
    }
}

// in-place rewrite: edges[j].y = dinv[src] * ew * dinv[c]
__global__ void coef_kernel(const int* __restrict__ ptr, int2* __restrict__ edges,
                            const float* __restrict__ dinv, int n) {
    int i = blockIdx.x * blockDim.x + threadIdx.x;
    if (i < n) {
        float dc = dinv[i];
        int e1 = ptr[i + 1];
        for (int j = ptr[i]; j < e1; ++j) {
            int2 t = edges[j];
            float w = __int_as_float(t.y);
            edges[j] = make_int2(t.x, __float_as_int(dinv[t.x] * w * dc));
        }
    }
}

// weight convert: W [K][N] row-major fp32 -> Wt_hi/Wt_lo [N][K] bf16 planes
__global__ void convw_kernel(const float* __restrict__ W, unsigned short* __restrict__ Wh,
                             unsigned short* __restrict__ Wl, int K, int N) {
    int idx = blockIdx.x * 256 + threadIdx.x;
    if (idx < N * K) {
        int n = idx / K, k = idx % K;
        unsigned short h, l;
        split_bf16(W[(size_t)k * N + n], h, l);
        Wh[idx] = h; Wl[idx] = l;
    }
}

// ---------------- aggregation kernels ----------------

// 256-dim aggregation, FEATURE-SPLIT: each launch covers 128 dims (d0 = 0 or 128)
// so the gathered working set halves (51 -> 25.6 MB) and XCD-L2 hit rate rises.
__global__ __launch_bounds__(256) void agg256_half_kernel(
        const float* __restrict__ x, const float* __restrict__ dinv,
        const int* __restrict__ ptr, const int2* __restrict__ edges,
        unsigned short* __restrict__ out_h, unsigned short* __restrict__ out_l, int d0) {
    int wv = threadIdx.x >> 6, lane = threadIdx.x & 63;
    int node = blockIdx.x * 4 + wv;
    if (node >= N_NODES) return;
    const float* xb = x + d0 + lane * 2;
    float di = dinv[node];
    float s = di * di;
    float2 v = *(const float2*)(xb + (size_t)node * IN_DIM);
    float ax = v.x * s, ay = v.y * s;
    int j = ptr[node], e1 = ptr[node + 1];
    for (; j + 3 < e1; j += 4) {
        int2 e0 = edges[j], e1_ = edges[j + 1], e2 = edges[j + 2], e3 = edges[j + 3];
        float2 u0 = *(const float2*)(xb + (size_t)e0.x * IN_DIM);
        float2 u1 = *(const float2*)(xb + (size_t)e1_.x * IN_DIM);
        float2 u2 = *(const float2*)(xb + (size_t)e2.x * IN_DIM);
        float2 u3 = *(const float2*)(xb + (size_t)e3.x * IN_DIM);
        float c0 = __int_as_float(e0.y), c1 = __int_as_float(e1_.y);
        float c2 = __int_as_float(e2.y), c3 = __int_as_float(e3.y);
        ax += c0 * u0.x + c1 * u1.x + c2 * u2.x + c3 * u3.x;
        ay += c0 * u0.y + c1 * u1.y + c2 * u2.y + c3 * u3.y;
    }
    for (; j < e1; ++j) {
        int2 e0 = edges[j];
        float c0 = __int_as_float(e0.y);
        float2 u0 = *(const float2*)(xb + (size_t)e0.x * IN_DIM);
        ax += c0 * u0.x; ay += c0 * u0.y;
    }
    unsigned short h0, l0, h1, l1;
    split_bf16(ax, h0, l0);
    split_bf16(ay, h1, l1);
    size_t o = (size_t)node * IN_DIM + d0;
    ((unsigned*)(out_h + o))[lane] = (unsigned)h0 | ((unsigned)h1 << 16);
    ((unsigned*)(out_l + o))[lane] = (unsigned)l0 | ((unsigned)l1 << 16);
}

// 128-dim aggregation fused with +bias and PReLU: one wave per node, float2 per lane.
__global__ __launch_bounds__(256) void agg128_epi_kernel(
        const float* __restrict__ xw, const float* __restrict__ dinv,
        const int* __restrict__ ptr, const int2* __restrict__ edges,
        const float* __restrict__ b2, const float* __restrict__ alphap,
        float* __restrict__ out) {
    int wv = threadIdx.x >> 6, lane = threadIdx.x & 63;
    int node = blockIdx.x * 4 + wv;
    if (node >= N_NODES) return;
    const float2* x2 = (const float2*)xw;
    float di = dinv[node];
    float s = di * di;
    float2 v = x2[node * 64 + lane];
    float ax = v.x * s, ay = v.y * s;
    int j = ptr[node], e1 = ptr[node + 1];
    for (; j + 3 < e1; j += 4) {
        int2 e0 = edges[j], e1_ = edges[j + 1], e2 = edges[j + 2], e3 = edges[j + 3];
        float2 u0 = x2[e0.x * 64 + lane];
        float2 u1 = x2[e1_.x * 64 + lane];
        float2 u2 = x2[e2.x * 64 + lane];
        float2 u3 = x2[e3.x * 64 + lane];
        float c0 = __int_as_float(e0.y), c1 = __int_as_float(e1_.y);
        float c2 = __int_as_float(e2.y), c3 = __int_as_float(e3.y);
        ax += c0 * u0.x + c1 * u1.x + c2 * u2.x + c3 * u3.x;
        ay += c0 * u0.y + c1 * u1.y + c2 * u2.y + c3 * u3.y;
    }
    for (; j < e1; ++j) {
        int2 e0 = edges[j];
        float c0 = __int_as_float(e0.y);
        float2 u0 = x2[e0.x * 64 + lane];
        ax += c0 * u0.x; ay += c0 * u0.y;
    }
    float alpha = alphap[0];
    float2 b = ((const float2*)b2)[lane];
    ax += b.x; ay += b.y;
    ax = (ax >= 0.f) ? ax : alpha * ax;
    ay = (ay >= 0.f) ? ay : alpha * ay;
    ((float2*)out)[node * 64 + lane] = make_float2(ax, ay);
}

// ---------------- bf16x3 split MFMA GEMM ----------------
// C[M,N] = A[M,K] @ B[N,K]^T, A/B as bf16 hi/lo planes. 128x128 tile, 4 waves,
// BK=64, single 64KB buffer. K-loop: barrier(DMA) -> ds_read all frags -> barrier
// -> issue next DMA -> 96 MFMAs. EPILOGUE: reuse the 64KB LDS to transpose the
// C tile so global stores are 16B-coalesced. Grid 1-D, bijective XCD swizzle.

__device__ __forceinline__ int swz(int row, int k /*ushort idx, mult of 8*/) {
    return ((row << 7) + (k << 1)) ^ ((row & 7) << 4);
}

__device__ __forceinline__ void gload16(const void* g, void* l) {
    __builtin_amdgcn_global_load_lds(
        (const __attribute__((address_space(1))) unsigned int*)g,
        (__attribute__((address_space(3))) unsigned int*)l, 16, 0, 0);
}

// stage one [128][64] bf16 plane; wave w covers rows [w*32, w*32+32)
__device__ __forceinline__ void stage_plane_async(
        const unsigned short* __restrict__ gbase,  // plane, row-major [*][K]
        unsigned short* lds, int K, int grow0, int k0, int wave, int lane) {
    int r8 = lane >> 3;                 // row within 8-row group == row&7 of lds row
    int kk = k0 + (((lane & 7) ^ r8) << 3);   // inverse-swizzled k (units of 8 bf16 = 16B)
#pragma unroll
    for (int t = 0; t < 4; ++t) {
        int rowblk = wave * 32 + t * 8;
        const unsigned short* g = gbase + (size_t)(grow0 + rowblk + r8) * K + kk;
        gload16(g, lds + (size_t)rowblk * 64);  // wave-uniform base; HW adds lane*16B
    }
}

template <int MODE>
__global__ __launch_bounds__(256, 2) void gemm_mfma_kernel(
        const unsigned short* __restrict__ A_hi, const unsigned short* __restrict__ A_lo,
        const unsigned short* __restrict__ B_hi, const unsigned short* __restrict__ B_lo,
        const float* __restrict__ bias, const float* __restrict__ alphap,
        unsigned short* __restrict__ Oh, unsigned short* __restrict__ Ol,
        float* __restrict__ Of, int M, int N, int K, int tilesX) {
    __shared__ unsigned short smem[4][8192];   // Ah, Al, Bh, Bl planes: [128][64] each
    unsigned short* Ah = smem[0];
    unsigned short* Al = smem[1];
    unsigned short* Bh = smem[2];
    unsigned short* Bl = smem[3];

    const int tid  = threadIdx.x;
    const int lane = tid & 63, wave = tid >> 6;
    const int wm = wave >> 1, wn = wave & 1;
    const int lr = lane & 15, lk = (lane >> 4) << 3;

    // bijective XCD-chunk swizzle (m204): consecutive swizzled ids stay on one XCD
    const int nwg = gridDim.x;
    const int q_ = nwg >> 3, r_ = nwg & 7;
    const int xcd = blockIdx.x & 7, idx = blockIdx.x >> 3;
    const int wg = ((xcd < r_) ? xcd * (q_ + 1) : r_ * (q_ + 1) + (xcd - r_) * q_) + idx;
    const int m0 = (wg / tilesX) * 128, n0 = (wg % tilesX) * 128;

    float4v acc[4][4] = {};

    stage_plane_async(A_hi, Ah, K, m0, 0, wave, lane);
    stage_plane_async(A_lo, Al, K, m0, 0, wave, lane);
    stage_plane_async(B_hi, Bh, K, n0, 0, wave, lane);
    stage_plane_async(B_lo, Bl, K, n0, 0, wave, lane);

    for (int k0 = 0; k0 < K; k0 += 64) {
        __syncthreads();   // drain DMA for this tile
        short8v ah[2][4], al[2][4], bh[2][4], bl[2][4];
#pragma unroll
        for (int q = 0; q < 2; ++q)
#pragma unroll
            for (int i = 0; i < 4; ++i) {
                ah[q][i] = *(const short8v*)((const char*)Ah + swz(wm * 64 + i * 16 + lr, q * 32 + lk));
                al[q][i] = *(const short8v*)((const char*)Al + swz(wm * 64 + i * 16 + lr, q * 32 + lk));
                bh[q][i] = *(const short8v*)((const char*)Bh + swz(wn * 64 + i * 16 + lr, q * 32 + lk));
                bl[q][i] = *(const short8v*)((const char*)Bl + swz(wn * 64 + i * 16 + lr, q * 32 + lk));
            }
        __syncthreads();   // all waves done reading -> safe to overwrite buffer
        if (k0 + 64 < K) {
            stage_plane_async(A_hi, Ah, K, m0, k0 + 64, wave, lane);
            stage_plane_async(A_lo, Al, K, m0, k0 + 64, wave, lane);
            stage_plane_async(B_hi, Bh, K, n0, k0 + 64, wave, lane);
            stage_plane_async(B_lo, Bl, K, n0, k0 + 64, wave, lane);
        }
#pragma unroll
        for (int q = 0; q < 2; ++q)
#pragma unroll
            for (int mi = 0; mi < 4; ++mi)
#pragma unroll
                for (int ni = 0; ni < 4; ++ni) {
                    acc[mi][ni] = __builtin_amdgcn_mfma_f32_16x16x32_bf16(ah[q][mi], bh[q][ni], acc[mi][ni], 0, 0, 0);
                    acc[mi][ni] = __builtin_amdgcn_mfma_f32_16x16x32_bf16(ah[q][mi], bl[q][ni], acc[mi][ni], 0, 0, 0);
                    acc[mi][ni] = __builtin_amdgcn_mfma_f32_16x16x32_bf16(al[q][mi], bh[q][ni], acc[mi][ni], 0, 0, 0);
                }
    }
    // after the final barrier above, all LDS reads are done -> safe to reuse smem.

    if (MODE == 1) {
        // pack h|(l<<16) into a [128][128] u32 LDS tile, then 16B-coalesced stores.
        unsigned* tr = (unsigned*)smem;
        const float alpha = alphap[0];
#pragma unroll
        for (int mi = 0; mi < 4; ++mi)
#pragma unroll
            for (int ni = 0; ni < 4; ++ni) {
                int lcol = wn * 64 + ni * 16 + lr;
                float bv = bias[n0 + lcol];
#pragma unroll
                for (int r = 0; r < 4; ++r) {
                    int lrow = wm * 64 + mi * 16 + (lane >> 4) * 4 + r;
                    float v = acc[mi][ni][r] + bv;
                    v = (v >= 0.f) ? v : alpha * v;
                    unsigned short h, l;
                    split_bf16(v, h, l);
                    tr[lrow * 128 + lcol] = (unsigned)h | ((unsigned)l << 16);
                }
            }
        __syncthreads();
#pragma unroll
        for (int c = 0; c < 8; ++c) {
            int chunk = tid + c * 256;          // 0..2047
            int row = chunk >> 4, cb = (chunk & 15) * 8;
            int grow = m0 + row;
            if (grow < M) {
                const unsigned* p = tr + row * 128 + cb;
                uint4v u0 = *(const uint4v*)p;
                uint4v u1 = *(const uint4v*)(p + 4);
                short8v hv, lv;
#pragma unroll
                for (int i = 0; i < 4; ++i) {
                    hv[i]     = (short)(u0[i] & 0xFFFFu); lv[i]     = (short)(u0[i] >> 16);
                    hv[i + 4] = (short)(u1[i] & 0xFFFFu); lv[i + 4] = (short)(u1[i] >> 16);
                }
                *(short8v*)(Oh + (size_t)grow * N + n0 + cb) = hv;
                *(short8v*)(Ol + (size_t)grow * N + n0 + cb) = lv;
            }
        }
    } else {
        // f32 [128][128] LDS tile (64 KB), then float4-coalesced stores.
        float* tr = (float*)smem;
#pragma unroll
        for (int mi = 0; mi < 4; ++mi)
#pragma unroll
            for (int ni = 0; ni < 4; ++ni) {
                int lcol = wn * 64 + ni * 16 + lr;
#pragma unroll
                for (int r = 0; r < 4; ++r) {
                    int lrow = wm * 64 + mi * 16 + (lane >> 4) * 4 + r;
                    tr[lrow * 128 + lcol] = acc[mi][ni][r];
                }
            }
        __syncthreads();
#pragma unroll
        for (int c = 0; c < 8; ++c) {
            int chunk = tid + c * 256;
            int row = chunk >> 4, cb = (chunk & 15) * 8;
            int grow = m0 + row;
            if (grow < M) {
                const float* p = tr + row * 128 + cb;
                float4 a = *(const float4*)p;
                float4 b = *(const float4*)(p + 4);
                *(float4*)(Of + (size_t)grow * N + n0 + cb)     = a;
                *(float4*)(Of + (size_t)grow * N + n0 + cb + 4) = b;
            }
        }
    }
}

// ---------------- launch ----------------

extern "C" void kernel_launch(void* const* d_in, const int* in_sizes, int n_in,
                              void* d_out, int out_size, void* d_ws, size_t ws_size,
                              hipStream_t stream) {
    const float* x     = (const float*)d_in[0];
    const float* eattr = (const float*)d_in[1];
    const float* W1    = (const float*)d_in[2];
    const float* b1    = (const float*)d_in[3];
    const float* W2    = (const float*)d_in[4];
    const float* b2    = (const float*)d_in[5];
    const float* alpha = (const float*)d_in[6];
    const int*   eidx  = (const int*)d_in[7];
    const int* row = eidx;
    const int* col = eidx + N_EDGES;
    float* out = (float*)d_out;

    // workspace layout (4B units); xw2 aliases aggx_h region (dead after gemm1)
    float* ws_f = (float*)d_ws;
    size_t off = 0;
    float* dinv  = ws_f + off; off += N_NODES;
    int2*  edges = (int2*)(ws_f + off); off += (size_t)2 * N_EDGES;   // (src, ew) -> (src, coef)
    unsigned short* aggx_h = (unsigned short*)(ws_f + off); off += (size_t)N_NODES * IN_DIM / 2; // bf16 plane
    unsigned short* aggx_l = (unsigned short*)(ws_f + off); off += (size_t)N_NODES * IN_DIM / 2;
    float* xw2 = (float*)aggx_h;  // 6.4M floats, fits in aggx_h plane region (dead after gemm1)
    unsigned short* feat1_h = (unsigned short*)(ws_f + off); off += (size_t)N_NODES * H1 / 2;
    unsigned short* feat1_l = (unsigned short*)(ws_f + off); off += (size_t)N_NODES * H1 / 2;
    unsigned short* W1t_h = (unsigned short*)(ws_f + off); off += (size_t)IN_DIM * H1 / 2;
    unsigned short* W1t_l = (unsigned short*)(ws_f + off); off += (size_t)IN_DIM * H1 / 2;
    unsigned short* W2t_h = (unsigned short*)(ws_f + off); off += (size_t)H1 * H2 / 2;
    unsigned short* W2t_l = (unsigned short*)(ws_f + off); off += (size_t)H1 * H2 / 2;
    int* cnt  = (int*)(ws_f + off); off += N_NODES;
    int* ptr  = (int*)(ws_f + off); off += N_NODES + 1;
    int* fill = (int*)(ws_f + off); off += N_NODES;
    int* part = (int*)(ws_f + off); off += N_NODES;
    int* bsum = (int*)(ws_f + off); off += 256;
    int* boff = (int*)(ws_f + off); off += 256;

    const int nodeBlocks = (N_NODES + 255) / 256;   // 196
    const int edgeBlocks = (N_EDGES + 255) / 256;   // 3125

    // 0) weight conversion (tiny)
    convw_kernel<<<(IN_DIM * H1 + 255) / 256, 256, 0, stream>>>(W1, W1t_h, W1t_l, IN_DIM, H1);
    convw_kernel<<<(H1 * H2 + 255) / 256, 256, 0, stream>>>(W2, W2t_h, W2t_l, H1, H2);

    // 1) CSR build: hist -> scan -> place(src,ew) -> deg/dinv from CSR -> coef in place
    hipMemsetAsync(cnt, 0, N_NODES * sizeof(int), stream);
    edge_hist_kernel<<<edgeBlocks, 256, 0, stream>>>(col, cnt, N_EDGES);
    scan_block_kernel<<<nodeBlocks, 256, 0, stream>>>(cnt, part, bsum, N_NODES);
    scan_tops_kernel<<<1, 256, 0, stream>>>(bsum, boff, nodeBlocks);
    scan_add_kernel<<<nodeBlocks, 256, 0, stream>>>(part, boff, ptr, fill, N_NODES);
    scatter_kernel<<<edgeBlocks, 256, 0, stream>>>(row, col, eattr, fill, edges, N_EDGES);
    degdinv_kernel<<<nodeBlocks, 256, 0, stream>>>(ptr, edges, dinv, N_NODES);
    coef_kernel<<<nodeBlocks, 256, 0, stream>>>(ptr, edges, dinv, N_NODES);

    // 2) layer 1: aggregate X in two feature-half passes -> bf16 hi/lo, then MFMA GEMM
    agg256_half_kernel<<<(N_NODES + 3) / 4, 256, 0, stream>>>(x, dinv, ptr, edges, aggx_h, aggx_l, 0);
    agg256_half_kernel<<<(N_NODES + 3) / 4, 256, 0, stream>>>(x, dinv, ptr, edges, aggx_h, aggx_l, 128);
    {
        int tilesX = H1 / 128, tilesY = (N_NODES + 127) / 128;   // 4 x 391
        gemm_mfma_kernel<1><<<tilesX * tilesY, 256, 0, stream>>>(
            aggx_h, aggx_l, W1t_h, W1t_l, b1, alpha, feat1_h, feat1_l, nullptr,
            N_NODES, H1, IN_DIM, tilesX);
    }

    // 3) layer 2: MFMA GEMM 512->128 (fp32 out), then aggregate (128-dim) + bias + PReLU
    {
        int tilesX = H2 / 128, tilesY = (N_NODES + 127) / 128;   // 1 x 391
        gemm_mfma_kernel<0><<<tilesX * tilesY, 256, 0, stream>>>(
            feat1_h, feat1_l, W2t_h, W2t_l, nullptr, nullptr, nullptr, nullptr, xw2,
            N_NODES, H2, H1, tilesX);
    }
    agg128_epi_kernel<<<(N_NODES + 3) / 4, 256, 0, stream>>>(xw2, dinv, ptr, edges, b2, alpha, out);
}